// Round 4
// baseline (471.701 us; speedup 1.0000x reference)
//
#include <hip/hip_runtime.h>

#define S_LEN 2048
#define NCH 32
#define KLAG 4

typedef float f32x4 __attribute__((ext_vector_type(4)));
typedef float f32x2 __attribute__((ext_vector_type(2)));

__device__ __forceinline__ float rlane(float v, int l) {
    return __int_as_float(__builtin_amdgcn_readlane(__float_as_int(v), l));
}
__device__ __forceinline__ f32x2 lo2(f32x4 v) { return __builtin_shufflevector(v, v, 0, 1); }
__device__ __forceinline__ f32x2 hi2(f32x4 v) { return __builtin_shufflevector(v, v, 2, 3); }

template<int CTRL, int RM>
__device__ __forceinline__ float dpp_add(float v) {
    int t = __builtin_amdgcn_update_dpp(0, __float_as_int(v), CTRL, RM, 0xF, true);
    return v + __int_as_float(t);
}
// sum across 64 lanes -> uniform scalar, VALU-only.
__device__ __forceinline__ float wave_sum(float v) {
    v = dpp_add<0x111, 0xF>(v);  // row_shr:1
    v = dpp_add<0x112, 0xF>(v);  // row_shr:2
    v = dpp_add<0x114, 0xF>(v);  // row_shr:4
    v = dpp_add<0x118, 0xF>(v);  // row_shr:8
    v = dpp_add<0x142, 0xA>(v);  // row_bcast:15
    v = dpp_add<0x143, 0xC>(v);  // row_bcast:31
    return rlane(v, 63);
}

#if __has_builtin(__builtin_amdgcn_exp2f)
#define EXP2F(x) __builtin_amdgcn_exp2f(x)
#else
#define EXP2F(x) exp2f(x)
#endif
#if __has_builtin(__builtin_amdgcn_logf)
#define LOG2F(x) __builtin_amdgcn_logf(x)
#else
#define LOG2F(x) __log2f(x)
#endif

// Conv form (validated r1-r3): x_t = sum_m [a_m e2_{t-1-m} + b_m sig_{t-1-m}] + G_t.
// r4 changes vs r3 (anti-spill round):
//  - amdgpu_waves_per_eu(2,2): VGPR budget 256 (was capped at 128 -> scratch
//    spill/reload on the per-step path; WRITE_SIZE 613MB was the tell).
//  - MATVEC unroll 16 -> 4 + sched_barrier(0) fences: bound the ds_read pressure
//    spike so inner-loop carried state is never spilled around it.
//  - 256B-aligned output stores via per-chunk lane-rotate (ds_bpermute, off-chain)
//    + carry register; removes 3-line split stores, makes WRITE_SIZE a clean
//    spill diagnostic (~17MB expected if spills are gone).
__attribute__((amdgpu_flat_work_group_size(256, 256)))
__attribute__((amdgpu_waves_per_eu(2, 2)))
__global__ void rnn_garch_conv4(
    const float* __restrict__ res,   // (B, S)
    const float* __restrict__ Wih,   // (64, 2)
    const float* __restrict__ bih,   // (64,)
    const float* __restrict__ Whh,   // (64, 64)
    const float* __restrict__ bhh,   // (64,)
    const float* __restrict__ fcw,   // (64,)
    const float* __restrict__ fcb,   // (1,)
    float* __restrict__ out)         // (B, S)
{
    // quad-major tables: tab[(q*64 + l)*4 + w] = T[l][q*4+w]
    __shared__ __align__(16) float tabC[4096];   // Tcur[l][i] = (i<=l) ? a'_{l-i} : 0
    __shared__ __align__(16) float tabP[4096];   // Tprev[l][i] = (i>l) ? a'_{64+l-i} : 0
    __shared__ __align__(16) float WlRot[4096];  // Whh stage, then beta-rotation table
    __shared__ __align__(16) float ubuf[4][64];  // per-wave u broadcast buffer
    __shared__ __align__(16) float ebuf[4][2][64]; // per-wave e^2 ring (2 slots)
    __shared__ float alp[64], betL[64];

    const int tid  = threadIdx.x;
    const int lane = tid & 63;
    const int wave = tid >> 6;
    const int b = blockIdx.x * 4 + wave;

    const float* __restrict__ row  = res + (size_t)b * S_LEN;
    float* __restrict__       orow = out + (size_t)b * S_LEN;

    const float K   = 1.44269504088896340736f;  // log2(e)
    const float LN2 = 0.69314718055994530942f;

    // ---- coop stage Whh -> LDS ----
    {
        const f32x4* w4 = (const f32x4*)Whh;
        f32x4* wl4 = (f32x4*)WlRot;
        for (int i = tid; i < 1024; i += 256) wl4[i] = w4[i];
    }
    // per-lane params
    const float w0l = Wih[lane * 2];
    const float w1l = Wih[lane * 2 + 1];
    const float bl  = bih[lane] + bhh[lane];
    const float fl  = fcw[lane];

    // ---- sigma0 = var(row, ddof=1) ----
    float s1 = 0.f, s2 = 0.f;
#pragma unroll 8
    for (int i = 0; i < S_LEN / 64; ++i) {
        const float x = row[i * 64 + lane];
        s1 += x;
        s2 = fmaf(x, x, s2);
    }
    s1 = wave_sum(s1);
    s2 = wave_sum(s2);
    const float mean = s1 * (1.0f / S_LEN);
    float sig = (s2 - s1 * mean) * (1.0f / (S_LEN - 1));   // sigma_0 (true scale)
    float carry = sig;               // aligned-store carry: sigma_{64c} for chunk c

    __syncthreads();

    // ---- W column into registers: wr[k] = W[k][lane] ----
    float wr[64];
#pragma unroll
    for (int k = 0; k < 64; ++k) wr[k] = WlRot[k * 64 + lane];

    // ---- u-chain (all waves redundantly; wave0 publishes K-scaled alp/betL) ----
    float b0 = K * wave_sum(fl * w1l);
    const float A0 = K * wave_sum(fl * w0l);
    const float C  = K * (wave_sum(fl * bl) + fcb[0]);
    if (tid == 0) { alp[0] = A0; betL[0] = b0; }
    float b1 = 0.f, b2 = 0.f, b3 = 0.f;
    float gpre = C;           // K*Gamma_{lane+1} (chunk 0)
    float ginf = C;           // K*Gamma_inf

    ubuf[wave][lane] = fl;
    asm volatile("" ::: "memory");
    const f32x4* uq4 = (const f32x4*)&ubuf[wave][0];
    float u;
    {
        float n0 = 0.f, n1 = 0.f, n2 = 0.f, n3 = 0.f;
#pragma unroll 4
        for (int q = 0; q < 16; ++q) {
            const f32x4 uq = uq4[q];
            n0 = fmaf(wr[4 * q + 0], uq.x, n0);
            n1 = fmaf(wr[4 * q + 1], uq.y, n1);
            n2 = fmaf(wr[4 * q + 2], uq.z, n2);
            n3 = fmaf(wr[4 * q + 3], uq.w, n3);
        }
        u = (n0 + n1) + (n2 + n3);
    }
#pragma unroll 1
    for (int i = 1; i < 64; ++i) {
        const float da = K * wave_sum(u * w0l);
        const float db = K * wave_sum(u * w1l);
        const float dg = K * wave_sum(u * bl);   // K*g_{i-1}
        if (tid == 0) { alp[i] = da; betL[i] = db; }
        if (i == 1) b1 = db; else if (i == 2) b2 = db; else if (i == 3) b3 = db;
        gpre += (lane >= i) ? dg : 0.f;
        ginf += dg;
        // u <- W^T u
        ubuf[wave][lane] = u;
        asm volatile("" ::: "memory");
        float n0 = 0.f, n1 = 0.f, n2 = 0.f, n3 = 0.f;
#pragma unroll 4
        for (int q = 0; q < 16; ++q) {
            const f32x4 uq = uq4[q];
            n0 = fmaf(wr[4 * q + 0], uq.x, n0);
            n1 = fmaf(wr[4 * q + 1], uq.y, n1);
            n2 = fmaf(wr[4 * q + 2], uq.z, n2);
            n3 = fmaf(wr[4 * q + 3], uq.w, n3);
        }
        u = (n0 + n1) + (n2 + n3);
    }
    __syncthreads();

    // ---- build Toeplitz tables + beta-rotation table (overwrites Whh region) ----
    for (int f = tid; f < 4096; f += 256) {
        const int w = f & 3;
        const int l = (f >> 2) & 63;
        const int q = f >> 8;
        const int col = q * 4 + w;               // = j for the rot table
        tabC[f] = (col <= l) ? alp[l - col] : 0.f;
        tabP[f] = (col > l) ? alp[64 + l - col] : 0.f;
        const int m = (l - col) & 63;
        WlRot[f] = (m >= KLAG) ? betL[m] : 0.f;  // rot[q*64+l][w] = beta'_{(l-j)&63}
    }
    __syncthreads();

    const f32x4* tC4 = (const f32x4*)tabC;
    const f32x4* tP4 = (const f32x4*)tabP;
    const f32x4* rot4 = (const f32x4*)WlRot;
    float* eb0 = &ebuf[wave][0][0];
    float* eb1 = &ebuf[wave][1][0];

#define MATVEC(OUT, CURP, PRVP) { \
    const f32x4* c4_ = (const f32x4*)(CURP); const f32x4* p4_ = (const f32x4*)(PRVP); \
    f32x2 mA = {0.f,0.f}, mB = {0.f,0.f}, mC = {0.f,0.f}, mD = {0.f,0.f}; \
    _Pragma("unroll 4") \
    for (int q = 0; q < 16; ++q) { \
        const f32x4 wc = tC4[q * 64 + lane]; const f32x4 ic = c4_[q]; \
        const f32x4 wp = tP4[q * 64 + lane]; const f32x4 ip = p4_[q]; \
        mA = __builtin_elementwise_fma(lo2(wc), lo2(ic), mA); \
        mB = __builtin_elementwise_fma(hi2(wc), hi2(ic), mB); \
        mC = __builtin_elementwise_fma(lo2(wp), lo2(ip), mC); \
        mD = __builtin_elementwise_fma(hi2(wp), hi2(ip), mD); } \
    const f32x2 ms_ = (mA + mB) + (mC + mD); OUT = ms_.x + ms_.y; }

    // ---- prologue: E'(0) -> acc, E'(1) -> eHold ----
    const float e0v = row[lane];
    const float e1v = row[64 + lane];
    eb1[lane] = 0.f;                 // e2(-1) = 0
    eb0[lane] = e0v * e0v;           // e2(0)
    asm volatile("" ::: "memory");
    float E0;
    MATVEC(E0, eb0, eb1);
    float acc = E0 + gpre;           // K*(E(0) + Gamma_{lane+1})
    eb1[lane] = e1v * e1v;           // e2(1)
    asm volatile("" ::: "memory");
    float eHold;
    MATVEC(eHold, eb1, eb0);
    eHold += ginf;                   // K*(E(1) + Gamma_inf)
    float ldn = row[128 + lane];     // e2 chunk 2 prefetch

    // prime lag pipeline (sigma_{-1..-3} = 0); all scaled by K
    float pre = rlane(acc, 0);
    float bp  = rlane(acc, 1);
    float xb  = rlane(acc, 2);
    float vout = 0.f;
    const int rotaddr = ((lane + 63) & 63) << 2;   // for aligned-store lane rotate

    // prime rot group 0
    f32x4 bq0 = rot4[lane];
    f32x4 bq1 = rot4[64 + lane];

#pragma unroll 1
    for (int c = 0; c < NCH; ++c) {
        const float eA = eHold;
        // stage e2(c+2) into slot c&1 (overwrites dead e2(c)); prefetch e2(c+3)
        float* ebw = (c & 1) ? eb1 : eb0;
        ebw[lane] = ldn * ldn;
        const int nc = (c + 3 < NCH - 1) ? (c + 3) : (NCH - 1);
        ldn = row[nc * 64 + lane];
        asm volatile("" ::: "memory");
        MATVEC(eHold, ((c & 1) ? eb1 : eb0), ((c & 1) ? eb0 : eb1));
        eHold += ginf;               // K*(E(c+2) + Gamma_inf)

        __builtin_amdgcn_sched_barrier(0);   // fence: keep MATVEC region out of the step loop

#pragma unroll 1
        for (int jg = 0; jg < 8; ++jg) {
            const int jb = jg << 3;
            // prefetch next group's rotation quads (chunk-invariant table, j cyclic)
            const int ng = ((jg + 1) & 7) << 1;
            const f32x4 nqA = rot4[ng * 64 + lane];
            const f32x4 nqB = rot4[(ng + 1) * 64 + lane];
#pragma unroll
            for (int k = 0; k < 8; ++k) {
                const int j = jb + k;
                const float bshv = (k < 4) ? bq0[k] : bq1[k - 4];
                const float xp = fmaf(b0, sig, pre);        // on-chain (K-scaled)
                acc = fmaf(bshv, sig, acc);                 // lag>=4 (wrap -> next chunk)
                const bool mine = (lane == j);
                acc = mine ? eA : acc;                      // reset-at-consume
                const float t = rlane(acc, (j + 3) & 63);   // hoisted 3 iters
                pre = fmaf(b1, sig, bp);
                bp  = fmaf(b2, sig, xb);
                xb  = fmaf(b3, sig, t);
                const float ee = EXP2F(-__builtin_fabsf(xp));   // 2^{-|x'|} = e^{-|x|}
                const float sp2 = fmaxf(xp, 0.f) + LOG2F(1.0f + ee);
                sig = fmaf(sp2, LN2, 1e-6f);                // true sigma
                vout = mine ? sig : vout;
            }
            bq0 = nqA; bq1 = nqB;
        }

        __builtin_amdgcn_sched_barrier(0);   // fence: store region

        // aligned 256B store: lane l gets sigma_{64c+l}
        // rot[l] = vout[(l-1)&63]; lane0 <- carry (sigma_{64c}); new carry = vout[63]
        const float rotv = __int_as_float(
            __builtin_amdgcn_ds_bpermute(rotaddr, __float_as_int(vout)));
        const float sv = (lane == 0) ? carry : rotv;
        orow[(c << 6) + lane] = sv;
        carry = rlane(vout, 63);             // sigma_{64(c+1)}
    }
#undef MATVEC
}

extern "C" void kernel_launch(void* const* d_in, const int* in_sizes, int n_in,
                              void* d_out, int out_size, void* d_ws, size_t ws_size,
                              hipStream_t stream) {
    const float* res = (const float*)d_in[0];
    const float* Wih = (const float*)d_in[1];
    const float* bih = (const float*)d_in[2];
    const float* Whh = (const float*)d_in[3];
    const float* bhh = (const float*)d_in[4];
    const float* fcw = (const float*)d_in[5];
    const float* fcb = (const float*)d_in[6];
    float* out = (float*)d_out;

    const int B = 2048;
    dim3 grid(B / 4), block(256);
    hipLaunchKernelGGL(rnn_garch_conv4, grid, block, 0, stream,
                       res, Wih, bih, Whh, bhh, fcw, fcb, out);
}

// Round 5
// 267.449 us; speedup vs baseline: 1.7637x; 1.7637x over previous
//
#include <hip/hip_runtime.h>

#define S_LEN 2048
#define NCH 32

typedef float f32x4 __attribute__((ext_vector_type(4)));

__device__ __forceinline__ float rlane(float v, int l) {
    return __int_as_float(__builtin_amdgcn_readlane(__float_as_int(v), l));
}

template<int CTRL, int RM>
__device__ __forceinline__ float dpp_add(float v) {
    int t = __builtin_amdgcn_update_dpp(0, __float_as_int(v), CTRL, RM, 0xF, true);
    return v + __int_as_float(t);
}
// sum across 64 lanes -> uniform scalar, VALU-only.
__device__ __forceinline__ float wave_sum(float v) {
    v = dpp_add<0x111, 0xF>(v);  // row_shr:1
    v = dpp_add<0x112, 0xF>(v);  // row_shr:2
    v = dpp_add<0x114, 0xF>(v);  // row_shr:4
    v = dpp_add<0x118, 0xF>(v);  // row_shr:8
    v = dpp_add<0x142, 0xA>(v);  // row_bcast:15
    v = dpp_add<0x143, 0xC>(v);  // row_bcast:31
    return rlane(v, 63);
}
// wavefront shift right by 1: lane l <- lane l-1, lane 0 <- 0 (bound_ctrl)
__device__ __forceinline__ float wfshr1(float v) {
    int t = __builtin_amdgcn_update_dpp(0, __float_as_int(v), 0x138, 0xF, 0xF, true);
    return __int_as_float(t);
}

#if __has_builtin(__builtin_amdgcn_exp2f)
#define EXP2F(x) __builtin_amdgcn_exp2f(x)
#else
#define EXP2F(x) exp2f(x)
#endif
#if __has_builtin(__builtin_amdgcn_logf)
#define LOG2F(x) __builtin_amdgcn_logf(x)
#else
#define LOG2F(x) __log2f(x)
#endif

// Conv form (validated r1-r4): x_t = sum_m [a_m e2_{t-1-m} + b_m sig_{t-1-m}] + G_t.
// r5: LDS-free main loop.
//  - KEY: tabC+tabP are jointly ONE circulant w[l][i] = a'_{(l-i)&63}. So the E
//    matvec has the same structure as the rotating-beta accumulation and is done
//    INCREMENTALLY: one fmaf per step (acc += a'_{(l-j)&63} * e2_j), with lags 0..3
//    folded off-chain via a per-chunk 4-tap FIR (E4v) since e2 has no feedback.
//    Wrapped reads (steps 61..63) add rlane(e4N, lane) as a compile-time correction;
//    reset value is plain K*Gamma_inf. The per-chunk 32KB/wave table traffic is gone.
//  - alpha/beta circulants in REGISTERS (aq/rq, 128 VGPRs), compile-time indexed via
//    a fully-unrolled 64-step loop (rule #20: no runtime indexing -> no scratch).
//  - u-chain matvecs back to FULL unroll (r4's 'unroll 4' made wr[] runtime-indexed
//    -> scratch -> 422MB FETCH; that was the whole regression).
__attribute__((amdgpu_flat_work_group_size(256, 256)))
__attribute__((amdgpu_waves_per_eu(2, 2)))
__global__ void rnn_garch_conv5(
    const float* __restrict__ res,   // (B, S)
    const float* __restrict__ Wih,   // (64, 2)
    const float* __restrict__ bih,   // (64,)
    const float* __restrict__ Whh,   // (64, 64)
    const float* __restrict__ bhh,   // (64,)
    const float* __restrict__ fcw,   // (64,)
    const float* __restrict__ fcb,   // (1,)
    float* __restrict__ out)         // (B, S)
{
    __shared__ __align__(16) float Wl[4096];     // staged Whh (setup only)
    __shared__ __align__(16) float ubuf[4][64];  // per-wave u broadcast buffer
    __shared__ float alp[64], betL[64];          // K-scaled alpha/beta

    const int tid  = threadIdx.x;
    const int lane = tid & 63;
    const int wave = tid >> 6;
    const int b = blockIdx.x * 4 + wave;

    const float* __restrict__ row  = res + (size_t)b * S_LEN;
    float* __restrict__       orow = out + (size_t)b * S_LEN;

    const float Kc  = 1.44269504088896340736f;  // log2(e)
    const float LN2 = 0.69314718055994530942f;

    // ---- coop stage Whh -> LDS ----
    {
        const f32x4* w4 = (const f32x4*)Whh;
        f32x4* wl4 = (f32x4*)Wl;
        for (int i = tid; i < 1024; i += 256) wl4[i] = w4[i];
    }
    // per-lane params
    const float w0l = Wih[lane * 2];
    const float w1l = Wih[lane * 2 + 1];
    const float bl  = bih[lane] + bhh[lane];
    const float fl  = fcw[lane];

    // ---- sigma0 = var(row, ddof=1) ----
    float s1 = 0.f, s2 = 0.f;
#pragma unroll 8
    for (int i = 0; i < S_LEN / 64; ++i) {
        const float x = row[i * 64 + lane];
        s1 += x;
        s2 = fmaf(x, x, s2);
    }
    s1 = wave_sum(s1);
    s2 = wave_sum(s2);
    const float mean = s1 * (1.0f / S_LEN);
    float sig = (s2 - s1 * mean) * (1.0f / (S_LEN - 1));   // sigma_0 (true scale)

    __syncthreads();

    // ---- W column into registers: wr[k] = W[k][lane] (FULL unroll: keep in regs) ----
    float wr[64];
#pragma unroll
    for (int k = 0; k < 64; ++k) wr[k] = Wl[k * 64 + lane];

    // ---- u-chain (all waves redundantly; wave0 publishes K-scaled alp/betL) ----
    float b0 = Kc * wave_sum(fl * w1l);
    const float A0 = Kc * wave_sum(fl * w0l);
    const float C  = Kc * (wave_sum(fl * bl) + fcb[0]);
    if (tid == 0) { alp[0] = A0; betL[0] = b0; }
    float b1 = 0.f, b2 = 0.f, b3 = 0.f;
    float gpre = C;           // K*Gamma_{lane+1} (chunk 0)
    float ginf = C;           // K*Gamma_inf

    ubuf[wave][lane] = fl;
    asm volatile("" ::: "memory");
    const f32x4* uq4 = (const f32x4*)&ubuf[wave][0];
    float u;
    {
        float n0 = 0.f, n1 = 0.f, n2 = 0.f, n3 = 0.f;
#pragma unroll
        for (int q = 0; q < 16; ++q) {
            const f32x4 uq = uq4[q];
            n0 = fmaf(wr[4 * q + 0], uq.x, n0);
            n1 = fmaf(wr[4 * q + 1], uq.y, n1);
            n2 = fmaf(wr[4 * q + 2], uq.z, n2);
            n3 = fmaf(wr[4 * q + 3], uq.w, n3);
        }
        u = (n0 + n1) + (n2 + n3);
    }
#pragma unroll 1
    for (int i = 1; i < 64; ++i) {
        const float da = Kc * wave_sum(u * w0l);
        const float db = Kc * wave_sum(u * w1l);
        const float dg = Kc * wave_sum(u * bl);   // K*g_{i-1}
        if (tid == 0) { alp[i] = da; betL[i] = db; }
        if (i == 1) b1 = db; else if (i == 2) b2 = db; else if (i == 3) b3 = db;
        gpre += (lane >= i) ? dg : 0.f;
        ginf += dg;
        // u <- W^T u
        ubuf[wave][lane] = u;
        asm volatile("" ::: "memory");
        float n0 = 0.f, n1 = 0.f, n2 = 0.f, n3 = 0.f;
#pragma unroll
        for (int q = 0; q < 16; ++q) {
            const f32x4 uq = uq4[q];
            n0 = fmaf(wr[4 * q + 0], uq.x, n0);
            n1 = fmaf(wr[4 * q + 1], uq.y, n1);
            n2 = fmaf(wr[4 * q + 2], uq.z, n2);
            n3 = fmaf(wr[4 * q + 3], uq.w, n3);
        }
        u = (n0 + n1) + (n2 + n3);
    }
    __syncthreads();

    // ---- circulant coefficient registers (lags < 4 zeroed; covered by E4v/pipeline) ----
    f32x4 aq[16], rq[16];
#pragma unroll
    for (int q = 0; q < 16; ++q) {
#pragma unroll
        for (int w = 0; w < 4; ++w) {
            const int m = (lane - (4 * q + w)) & 63;
            const bool z = (m < 4);
            aq[q][w] = z ? 0.f : alp[m];
            rq[q][w] = z ? 0.f : betL[m];
        }
    }
    const float aA0 = alp[0], aA1 = alp[1], aA2 = alp[2], aA3 = alp[3];

// E4 FIR: DST[l] = sum_{m=0..3} a'_m e2[l-m], prev-chunk boundary via P61..P63 scalars
#define E4BUILD(DST, EQ, P61, P62, P63) { \
    const float s1_ = wfshr1(EQ); \
    const float s2_ = wfshr1(s1_); \
    const float s3_ = wfshr1(s2_); \
    float e4_ = aA0 * (EQ); \
    e4_ = fmaf(aA1, s1_, e4_); \
    e4_ = fmaf(aA2, s2_, e4_); \
    e4_ = fmaf(aA3, s3_, e4_); \
    const float f0_ = fmaf(aA1, (P63), fmaf(aA2, (P62), aA3 * (P61))); \
    const float f1_ = fmaf(aA2, (P63), aA3 * (P62)); \
    const float f2_ = aA3 * (P63); \
    e4_ = (lane == 0) ? e4_ + f0_ : e4_; \
    e4_ = (lane == 1) ? e4_ + f1_ : e4_; \
    e4_ = (lane == 2) ? e4_ + f2_ : e4_; \
    (DST) = e4_; }

    // ---- prologue ----
    const float r0v = row[lane];
    const float r1v = row[64 + lane];
    float eqC = r0v * r0v;           // e2 chunk 0
    float eqN = r1v * r1v;           // e2 chunk 1
    float ldn = row[128 + lane];     // raw chunk 2

    float e4C;
    E4BUILD(e4C, eqC, 0.f, 0.f, 0.f);
    float acc = gpre + e4C;          // K*Gamma_{lane+1} + lags 0..3 of chunk 0

    {
        const float p63 = rlane(eqC, 63), p62 = rlane(eqC, 62), p61 = rlane(eqC, 61);
        E4BUILD(e4C, eqN, p61, p62, p63);   // reuse e4C as e4N below via rename
    }
    float e4N = e4C;                 // E4v for chunk 1

    // prime lag pipeline (sigma_{-1..-3} = 0); all K-scaled
    float pre = rlane(acc, 0);
    float bp  = rlane(acc, 1);
    float xb  = rlane(acc, 2);
    float vout = 0.f;
    const int rotaddr = ((lane + 63) & 63) << 2;   // aligned-store lane rotate

#pragma unroll 1
    for (int c = 0; c < NCH; ++c) {
        const float sigchunk = sig;  // sigma_{64c} for the aligned store

#pragma unroll
        for (int j = 0; j < 64; ++j) {
            const float bsh = rq[j >> 2][j & 3];   // beta'_{(lane-j)&63}
            const float ash = aq[j >> 2][j & 3];   // alpha'_{(lane-j)&63}
            const float e2j = rlane(eqC, j);       // e2_{64c+j} (uniform, off-chain)
            const float xp = fmaf(b0, sig, pre);   // on-chain (K-scaled)
            acc = fmaf(bsh, sig, acc);             // sigma lags >=4 (wrap -> next chunk)
            acc = fmaf(ash, e2j, acc);             // e2 lags >=4 (wrap -> next chunk)
            const bool mine = (lane == j);
            acc = mine ? ginf : acc;               // reset-at-consume (base = K*Gamma_inf)
            float t = rlane(acc, (j + 3) & 63);    // hoisted 3 iters
            if (j >= 61) t += rlane(e4N, j - 61);  // wrapped read: next chunk lags 0..3
            pre = fmaf(b1, sig, bp);
            bp  = fmaf(b2, sig, xb);
            xb  = fmaf(b3, sig, t);
            const float ee = EXP2F(-__builtin_fabsf(xp));   // 2^{-|x'|} = e^{-|x|}
            const float sp2 = fmaxf(xp, 0.f) + LOG2F(1.0f + ee);
            sig = fmaf(sp2, LN2, 1e-6f);           // true sigma
            vout = mine ? sig : vout;              // lane j holds sigma_{64c+j+1}
        }

        // aligned 256B store: lane l <- sigma_{64c+l}
        const float rotv = __int_as_float(
            __builtin_amdgcn_ds_bpermute(rotaddr, __float_as_int(vout)));
        orow[(c << 6) + lane] = (lane == 0) ? sigchunk : rotv;

        // advance: fold chunk-(c+1) lags 0..3 into acc (lanes 0..2 wiped by their
        // reset before re-use -> no double count); slide e2 window; build next E4v
        acc += e4N;
        const float p63 = rlane(eqN, 63), p62 = rlane(eqN, 62), p61 = rlane(eqN, 61);
        eqC = eqN;
        eqN = ldn * ldn;
        const int nc = (c + 3 < NCH) ? (c + 3) : (NCH - 1);
        ldn = row[nc * 64 + lane];
        E4BUILD(e4N, eqN, p61, p62, p63);
    }
#undef E4BUILD
}

extern "C" void kernel_launch(void* const* d_in, const int* in_sizes, int n_in,
                              void* d_out, int out_size, void* d_ws, size_t ws_size,
                              hipStream_t stream) {
    const float* res = (const float*)d_in[0];
    const float* Wih = (const float*)d_in[1];
    const float* bih = (const float*)d_in[2];
    const float* Whh = (const float*)d_in[3];
    const float* bhh = (const float*)d_in[4];
    const float* fcw = (const float*)d_in[5];
    const float* fcb = (const float*)d_in[6];
    float* out = (float*)d_out;

    const int B = 2048;
    dim3 grid(B / 4), block(256);
    hipLaunchKernelGGL(rnn_garch_conv5, grid, block, 0, stream,
                       res, Wih, bih, Whh, bhh, fcw, fcb, out);
}